// Round 2
// baseline (531.272 us; speedup 1.0000x reference)
//
#include <hip/hip_runtime.h>
#include <hip/hip_bf16.h>
#include <stdint.h>

// y[b,s,o] = sum_i x[b,s,i] * (w[o,i]*mask[o,i]) + bias[o]
// M = 8192 (B*S), N = 4096 (D_OUT), K = 4096 (D_IN). fp32 in/out, bf16 MFMA.
#define M_DIM 8192
#define N_DIM 4096
#define K_DIM 4096

#define BM 256
#define BN 256
#define BK 64
#define NT (K_DIM / BK)   // 64 K-tiles

typedef __attribute__((ext_vector_type(8))) __bf16 bf16x8;
typedef __attribute__((ext_vector_type(4))) float floatx4;

// ---------- fp32 -> bf16 (RNE) packing helpers ----------
__device__ inline unsigned f2b(float f) {
    union { float f; unsigned u; } v; v.f = f;
    return (v.u + 0x7FFFu + ((v.u >> 16) & 1u)) >> 16;   // RNE; inputs finite
}
__device__ inline unsigned pk2(float lo, float hi) {
    return (f2b(lo) & 0xFFFFu) | (f2b(hi) << 16);
}

// Async global->LDS, 16B/lane. Low 32 bits of flat shared ptr == LDS offset.
__device__ inline void async_load16(const void* g, void* l) {
    __builtin_amdgcn_global_load_lds(
        (const __attribute__((address_space(1))) unsigned int*)(unsigned long long)g,
        (__attribute__((address_space(3))) unsigned int*)(unsigned int)(unsigned long long)l,
        16, 0, 0);
}

#define SFENCE() asm volatile("" ::: "memory")

// ---------- Pass 1: merged cvt — xb = bf16(x); wb = bf16(w*mask) ----------
// One launch. Blocks [0,XBLK) stream x (24B/iter/thread), rest stream w+mask
// (40B/iter/thread). 16B loads, 16B stores.
#define CVT_GRID 2048
#define CVT_XBLK 1152
__global__ __launch_bounds__(256)
void cvt_all(const float4* __restrict__ x, const float4* __restrict__ w,
             const float4* __restrict__ m, uint4* __restrict__ xb,
             uint4* __restrict__ wb, int nx8, int nw8) {
    if ((int)blockIdx.x < CVT_XBLK) {
        int i = blockIdx.x * 256 + threadIdx.x;
        const int stride = CVT_XBLK * 256;
        for (; i < nx8; i += stride) {
            float4 a = x[2 * i], b = x[2 * i + 1];
            uint4 o;
            o.x = pk2(a.x, a.y); o.y = pk2(a.z, a.w);
            o.z = pk2(b.x, b.y); o.w = pk2(b.z, b.w);
            xb[i] = o;
        }
    } else {
        int i = ((int)blockIdx.x - CVT_XBLK) * 256 + threadIdx.x;
        const int stride = (CVT_GRID - CVT_XBLK) * 256;
        for (; i < nw8; i += stride) {
            float4 w0 = w[2 * i], w1 = w[2 * i + 1];
            float4 m0 = m[2 * i], m1 = m[2 * i + 1];
            uint4 o;
            o.x = pk2(w0.x * m0.x, w0.y * m0.y);
            o.y = pk2(w0.z * m0.z, w0.w * m0.w);
            o.z = pk2(w1.x * m1.x, w1.y * m1.y);
            o.w = pk2(w1.z * m1.z, w1.w * m1.w);
            wb[i] = o;
        }
    }
}

// ---------- Pass 2: 256x256 8-phase GEMM, C = A @ B^T + bias ----------
// 8 waves (2M x 4N), per-wave 128x64 output = 8x4 frags of 16x16.
// LDS: 2 dbuf x {A,B} x 2 halves x [128][64] bf16 = 128 KiB.
//
// kk-split phase schedule (balanced ds_reads 8/8/4/4 per wave per K-tile):
//   P1: read af[0..3]k0 + B[0..3]k0 (8) | stage A(nb)r1 (s+1) | MFMA i0-3 k0
//   P2: read af[0..3]k1 + B[0..3]k1 (8) |                     | MFMA i0-3 k1
//   P3: read af[4..7]k0 (4) | stage A(b)r0 + B(b)h0 (s+2, 4x) | MFMA i4-7 k0
//   P4: read af[4..7]k1 (4) | stage B(b)h1 (s+2, 2x)          | MFMA i4-7 k1
// B frags (both kk) held in regs across the tile (32 VGPR).
// Restage safety: A(b)r0 & B(b) last read in P2 -> restaged P3/P4 (after the
// P2 post-MFMA barrier). A(nb)r1 last read in tile s-1 P4 -> restaged P1(s).
// vmcnt(6) once per tile at P4: leaves exactly tile-(s+2)'s 6 loads in
// flight; everything for tile s+1 has landed.
__global__ __launch_bounds__(512, 2)
void gemm_8phase(const __hip_bfloat16* __restrict__ A,
                 const __hip_bfloat16* __restrict__ B,
                 const float* __restrict__ bias,
                 float* __restrict__ C) {
    __shared__ __hip_bfloat16 As[2][2][128][64];   // [buf][half][row][col] 64 KiB
    __shared__ __hip_bfloat16 Bs[2][2][128][64];   // 64 KiB

    const int t    = threadIdx.x;
    const int lane = t & 63;
    const int wave = t >> 6;        // 0..7
    const int wm   = wave >> 2;     // 0..1 : M-half of tile
    const int wn   = wave & 3;      // 0..3 : N-quarter of tile
    const int lm   = lane & 15;
    const int h4   = lane >> 4;     // 0..3

    // XCD-aware bijective swizzle: 512 wgs = 8 XCDs x 64
    const int wg = (blockIdx.x & 7) * 64 + (blockIdx.x >> 3);
    const int m0 = (wg >> 4) * BM;  // 32 m-tiles
    const int n0 = (wg & 15) * BN;  // 16 n-tiles

    // Staging map: thread t stages 16B chunk (t&7) of row (t>>3) of a 64-row
    // unit. Source chunk is inverse-swizzled (involution), LDS dest linear.
    const int srow = t >> 3;            // 0..63
    const int schk = t & 7;
    const int sx   = schk ^ (srow & 7);

    const __hip_bfloat16* gA[2][2];
    const __hip_bfloat16* gB[2][2];
#pragma unroll
    for (int h = 0; h < 2; h++)
#pragma unroll
        for (int r = 0; r < 2; r++) {
            gA[h][r] = A + (size_t)(m0 + h * 128 + r * 64 + srow) * K_DIM + sx * 8;
            gB[h][r] = B + (size_t)(n0 + h * 128 + r * 64 + srow) * K_DIM + sx * 8;
        }

#define STAGE_A(b, h, r, tt) \
    async_load16(gA[h][r] + (tt) * BK, &As[b][h][(r) * 64 + srow][schk * 8])
#define STAGE_B(b, h, r, tt) \
    async_load16(gB[h][r] + (tt) * BK, &Bs[b][h][(r) * 64 + srow][schk * 8])

    // Frag reads: row-in-half = i*16+lm, chunk = kk*4+h4, swizzled by row&7.
    const int cs0 = ((h4)     ^ (lm & 7)) * 8;   // kk=0 element offset
    const int cs1 = ((4 + h4) ^ (lm & 7)) * 8;   // kk=1

#define LDA(b, i, kk) \
    (*(const bf16x8*)&As[b][wm][(i) * 16 + lm][(kk) ? cs1 : cs0])
#define LDB(b, j, kk) \
    (*(const bf16x8*)&Bs[b][wn >> 1][(wn & 1) * 64 + (j) * 16 + lm][(kk) ? cs1 : cs0])

    floatx4 acc[8][4] = {};
    bf16x8 af[4], bfr[4][2];

    // ---- prologue: tile0 complete (8) + tile1 {A r0, B h0, B h1} (6) ----
    STAGE_A(0, 0, 0, 0); STAGE_A(0, 1, 0, 0);
    STAGE_A(0, 0, 1, 0); STAGE_A(0, 1, 1, 0);
    STAGE_B(0, 0, 0, 0); STAGE_B(0, 0, 1, 0);
    STAGE_B(0, 1, 0, 0); STAGE_B(0, 1, 1, 0);
    STAGE_A(1, 0, 0, 1); STAGE_A(1, 1, 0, 1);
    STAGE_B(1, 0, 0, 1); STAGE_B(1, 0, 1, 1);
    STAGE_B(1, 1, 0, 1); STAGE_B(1, 1, 1, 1);
    asm volatile("s_waitcnt vmcnt(6)" ::: "memory");  // tile0 landed
    __builtin_amdgcn_s_barrier();
    SFENCE();

    for (int s = 0; s < NT; ++s) {
        const int b  = s & 1;
        const int nb = b ^ 1;

        // ---------------- P1: i0-3 x j0-3, k0 ----------------
#pragma unroll
        for (int i = 0; i < 4; i++) af[i] = LDA(b, i, 0);
#pragma unroll
        for (int j = 0; j < 4; j++) bfr[j][0] = LDB(b, j, 0);
        if (s + 1 < NT) { STAGE_A(nb, 0, 1, s + 1); STAGE_A(nb, 1, 1, s + 1); }
        asm volatile("s_waitcnt lgkmcnt(4)" ::: "memory");
        SFENCE(); __builtin_amdgcn_s_barrier();
        asm volatile("s_waitcnt lgkmcnt(0)" ::: "memory");
        __builtin_amdgcn_s_setprio(1);
#pragma unroll
        for (int i = 0; i < 4; i++)
#pragma unroll
            for (int j = 0; j < 4; j++)
                acc[i][j] = __builtin_amdgcn_mfma_f32_16x16x32_bf16(
                    af[i], bfr[j][0], acc[i][j], 0, 0, 0);
        __builtin_amdgcn_s_setprio(0);
        SFENCE(); __builtin_amdgcn_s_barrier(); SFENCE();

        // ---------------- P2: i0-3 x j0-3, k1 ----------------
#pragma unroll
        for (int i = 0; i < 4; i++) af[i] = LDA(b, i, 1);
#pragma unroll
        for (int j = 0; j < 4; j++) bfr[j][1] = LDB(b, j, 1);
        asm volatile("s_waitcnt lgkmcnt(4)" ::: "memory");
        SFENCE(); __builtin_amdgcn_s_barrier();
        asm volatile("s_waitcnt lgkmcnt(0)" ::: "memory");
        __builtin_amdgcn_s_setprio(1);
#pragma unroll
        for (int i = 0; i < 4; i++)
#pragma unroll
            for (int j = 0; j < 4; j++)
                acc[i][j] = __builtin_amdgcn_mfma_f32_16x16x32_bf16(
                    af[i], bfr[j][1], acc[i][j], 0, 0, 0);
        __builtin_amdgcn_s_setprio(0);
        SFENCE(); __builtin_amdgcn_s_barrier(); SFENCE();

        // ---------------- P3: i4-7 x j0-3, k0 ----------------
#pragma unroll
        for (int i = 0; i < 4; i++) af[i] = LDA(b, 4 + i, 0);
        if (s + 2 < NT) {
            STAGE_A(b, 0, 0, s + 2); STAGE_A(b, 1, 0, s + 2);
            STAGE_B(b, 0, 0, s + 2); STAGE_B(b, 0, 1, s + 2);
        }
        SFENCE(); __builtin_amdgcn_s_barrier();
        asm volatile("s_waitcnt lgkmcnt(0)" ::: "memory");
        __builtin_amdgcn_s_setprio(1);
#pragma unroll
        for (int i = 0; i < 4; i++)
#pragma unroll
            for (int j = 0; j < 4; j++)
                acc[4 + i][j] = __builtin_amdgcn_mfma_f32_16x16x32_bf16(
                    af[i], bfr[j][0], acc[4 + i][j], 0, 0, 0);
        __builtin_amdgcn_s_setprio(0);
        SFENCE(); __builtin_amdgcn_s_barrier(); SFENCE();

        // ---------------- P4: i4-7 x j0-3, k1 ----------------
#pragma unroll
        for (int i = 0; i < 4; i++) af[i] = LDA(b, 4 + i, 1);
        if (s + 2 < NT) { STAGE_B(b, 1, 0, s + 2); STAGE_B(b, 1, 1, s + 2); }
        asm volatile("s_waitcnt lgkmcnt(0)" ::: "memory");
        __builtin_amdgcn_s_setprio(1);
#pragma unroll
        for (int i = 0; i < 4; i++)
#pragma unroll
            for (int j = 0; j < 4; j++)
                acc[4 + i][j] = __builtin_amdgcn_mfma_f32_16x16x32_bf16(
                    af[i], bfr[j][1], acc[4 + i][j], 0, 0, 0);
        __builtin_amdgcn_s_setprio(0);
        if (s + 2 < NT) asm volatile("s_waitcnt vmcnt(6)" ::: "memory");
        else            asm volatile("s_waitcnt vmcnt(0)" ::: "memory");
        SFENCE(); __builtin_amdgcn_s_barrier(); SFENCE();
    }

    // ---- epilogue: C/D layout col = lane&15, row = (lane>>4)*4 + reg ----
    float bv[4];
#pragma unroll
    for (int j = 0; j < 4; j++)
        bv[j] = bias[n0 + wn * 64 + j * 16 + lm];
    const int row_base = m0 + wm * 128 + h4 * 4;
    const int col_base = n0 + wn * 64 + lm;
#pragma unroll
    for (int i = 0; i < 8; i++)
#pragma unroll
        for (int j = 0; j < 4; j++) {
            const int col = col_base + j * 16;
#pragma unroll
            for (int r = 0; r < 4; r++)
                C[(size_t)(row_base + i * 16 + r) * N_DIM + col] =
                    acc[i][j][r] + bv[j];
        }
}

extern "C" void kernel_launch(void* const* d_in, const int* in_sizes, int n_in,
                              void* d_out, int out_size, void* d_ws, size_t ws_size,
                              hipStream_t stream) {
    const float* x    = (const float*)d_in[0];   // [4,2048,4096] fp32
    const float* w    = (const float*)d_in[1];   // [4096,4096] fp32
    const float* bias = (const float*)d_in[2];   // [4096] fp32
    const float* mask = (const float*)d_in[3];   // [4096,4096] fp32
    float* out = (float*)d_out;                  // [8192,4096] fp32

    __hip_bfloat16* xb = (__hip_bfloat16*)d_ws;                    // 64 MiB
    __hip_bfloat16* wb = xb + (size_t)M_DIM * K_DIM;               // 32 MiB

    cvt_all<<<dim3(CVT_GRID), dim3(256), 0, stream>>>(
        (const float4*)x, (const float4*)w, (const float4*)mask,
        (uint4*)xb, (uint4*)wb, M_DIM * K_DIM / 8, N_DIM * K_DIM / 8);
    gemm_8phase<<<dim3(512), dim3(512), 0, stream>>>(xb, wb, bias, out);
}

// Round 3
// 527.158 us; speedup vs baseline: 1.0078x; 1.0078x over previous
//
#include <hip/hip_runtime.h>
#include <hip/hip_bf16.h>
#include <stdint.h>

// y[b,s,o] = sum_i x[b,s,i] * (w[o,i]*mask[o,i]) + bias[o]
// M = 8192 (B*S), N = 4096 (D_OUT), K = 4096 (D_IN). fp32 in/out, bf16 MFMA.
#define M_DIM 8192
#define N_DIM 4096
#define K_DIM 4096

#define BM 256
#define BN 256
#define BK 64
#define NT (K_DIM / BK)   // 64 K-tiles

typedef __attribute__((ext_vector_type(8))) __bf16 bf16x8;
typedef __attribute__((ext_vector_type(4))) float floatx4;

// ---------- fp32 -> bf16 (RNE) packing helpers ----------
__device__ inline unsigned f2b(float f) {
    union { float f; unsigned u; } v; v.f = f;
    return (v.u + 0x7FFFu + ((v.u >> 16) & 1u)) >> 16;   // RNE; inputs finite
}
__device__ inline unsigned pk2(float lo, float hi) {
    return (f2b(lo) & 0xFFFFu) | (f2b(hi) << 16);
}

// Async global->LDS, 16B/lane. Low 32 bits of flat shared ptr == LDS offset.
__device__ inline void async_load16(const void* g, void* l) {
    __builtin_amdgcn_global_load_lds(
        (const __attribute__((address_space(1))) unsigned int*)(unsigned long long)g,
        (__attribute__((address_space(3))) unsigned int*)(unsigned int)(unsigned long long)l,
        16, 0, 0);
}

#define SFENCE() asm volatile("" ::: "memory")

// ---------- Pass 1: merged cvt — xb = bf16(x); wb = bf16(w*mask) ----------
// Traffic: x-path 201 MB, w-path 168 MB -> split blocks 1120 / 928.
#define CVT_GRID 2048
#define CVT_XBLK 1120
__global__ __launch_bounds__(256)
void cvt_all(const float4* __restrict__ x, const float4* __restrict__ w,
             const float4* __restrict__ m, uint4* __restrict__ xb,
             uint4* __restrict__ wb, int nx8, int nw8) {
    if ((int)blockIdx.x < CVT_XBLK) {
        int i = blockIdx.x * 256 + threadIdx.x;
        const int stride = CVT_XBLK * 256;
        for (; i < nx8; i += stride) {
            float4 a = x[2 * i], b = x[2 * i + 1];
            uint4 o;
            o.x = pk2(a.x, a.y); o.y = pk2(a.z, a.w);
            o.z = pk2(b.x, b.y); o.w = pk2(b.z, b.w);
            xb[i] = o;
        }
    } else {
        int i = ((int)blockIdx.x - CVT_XBLK) * 256 + threadIdx.x;
        const int stride = (CVT_GRID - CVT_XBLK) * 256;
        for (; i < nw8; i += stride) {
            float4 w0 = w[2 * i], w1 = w[2 * i + 1];
            float4 m0 = m[2 * i], m1 = m[2 * i + 1];
            uint4 o;
            o.x = pk2(w0.x * m0.x, w0.y * m0.y);
            o.y = pk2(w0.z * m0.z, w0.w * m0.w);
            o.z = pk2(w1.x * m1.x, w1.y * m1.y);
            o.w = pk2(w1.z * m1.z, w1.w * m1.w);
            wb[i] = o;
        }
    }
}

// ---------- Pass 2: 256x256 8-phase GEMM, C = A @ B^T + bias ----------
// Faithful m201 template: 2 K-tiles per loop iteration (static LDS buffer
// indices), quadrant MFMA phases with {12,4,8,0} ds_reads, 2 stages/phase,
// vmcnt(6) once per K-tile at P4.
//
// Unit-free schedule (tile s in buf b, tile s+1 in buf nb):
//   P1: read af0-3 + b01 (12) | stage A(nb,*,r1, s+1)  [A*r1(nb) freed P3 prev]
//   P2: read b23 (4)          | stage A(b,*,r0, s+2)   [freed after P1]
//   P3: read af4-7 (8)        | stage B(b,0,*, s+2)    [freed after P2]
//   P4: (0 reads)             | stage B(b,1,*, s+2)    [freed after P2]
//       MFMA Q11; vmcnt(6) -> tile s+1 fully landed, 6 loads (s+2) in flight.
__global__ __launch_bounds__(512, 2)
void gemm_8phase(const __hip_bfloat16* __restrict__ A,
                 const __hip_bfloat16* __restrict__ B,
                 const float* __restrict__ bias,
                 float* __restrict__ C) {
    __shared__ __hip_bfloat16 As[2][2][128][64];   // [buf][half][row][col] 64 KiB
    __shared__ __hip_bfloat16 Bs[2][2][128][64];   // 64 KiB

    const int t    = threadIdx.x;
    const int lane = t & 63;
    const int wave = t >> 6;        // 0..7
    const int wm   = wave >> 2;     // 0..1 : M-half of tile
    const int wn   = wave & 3;      // 0..3 : N-quarter of tile
    const int lm   = lane & 15;
    const int h4   = lane >> 4;     // 0..3

    // XCD-aware bijective swizzle: 512 wgs = 8 XCDs x 64
    const int wg = (blockIdx.x & 7) * 64 + (blockIdx.x >> 3);
    const int m0 = (wg >> 4) * BM;  // 32 m-tiles
    const int n0 = (wg & 15) * BN;  // 16 n-tiles

    // Staging map: thread t stages 16B chunk (t&7) of row (t>>3) of a 64-row
    // unit. Source chunk is inverse-swizzled (involution), LDS dest linear.
    const int srow = t >> 3;            // 0..63
    const int schk = t & 7;
    const int sx   = schk ^ (srow & 7);

    const __hip_bfloat16* gA[2][2];
    const __hip_bfloat16* gB[2][2];
#pragma unroll
    for (int h = 0; h < 2; h++)
#pragma unroll
        for (int r = 0; r < 2; r++) {
            gA[h][r] = A + (size_t)(m0 + h * 128 + r * 64 + srow) * K_DIM + sx * 8;
            gB[h][r] = B + (size_t)(n0 + h * 128 + r * 64 + srow) * K_DIM + sx * 8;
        }

#define STAGE_A(b, h, r, tt) \
    async_load16(gA[h][r] + (size_t)(tt) * BK, &As[b][h][(r) * 64 + srow][schk * 8])
#define STAGE_B(b, h, r, tt) \
    async_load16(gB[h][r] + (size_t)(tt) * BK, &Bs[b][h][(r) * 64 + srow][schk * 8])

    // Frag reads: row-in-half = i*16+lm, chunk = kk*4+h4, swizzled by row&7.
    const int cs0 = ((h4)     ^ (lm & 7)) * 8;   // kk=0 element offset
    const int cs1 = ((4 + h4) ^ (lm & 7)) * 8;   // kk=1

#define LDA(b, i, kk) \
    (*(const bf16x8*)&As[b][wm][(i) * 16 + lm][(kk) ? cs1 : cs0])
#define LDB(b, j, kk) \
    (*(const bf16x8*)&Bs[b][wn >> 1][(wn & 1) * 64 + (j) * 16 + lm][(kk) ? cs1 : cs0])

    floatx4 acc[8][4] = {};
    bf16x8 af[4][2], b01[2][2], b23[2][2];

#define MFMA16(bi, bj, B_)                                                    \
    __builtin_amdgcn_s_setprio(1);                                            \
    _Pragma("unroll") for (int i = 0; i < 4; i++)                             \
    _Pragma("unroll") for (int j = 0; j < 2; j++)                             \
    _Pragma("unroll") for (int kk = 0; kk < 2; kk++)                          \
        acc[(bi) + i][(bj) + j] = __builtin_amdgcn_mfma_f32_16x16x32_bf16(    \
            af[i][kk], B_[j][kk], acc[(bi) + i][(bj) + j], 0, 0, 0);          \
    __builtin_amdgcn_s_setprio(0);

#define KTILE(b, nb, ss)                                                      \
  { const int s_ = (ss);                                                      \
    /* -------- P1: Q00 -------- */                                           \
    _Pragma("unroll") for (int i = 0; i < 4; i++) {                           \
        af[i][0] = LDA(b, i, 0); af[i][1] = LDA(b, i, 1); }                   \
    _Pragma("unroll") for (int j = 0; j < 2; j++) {                           \
        b01[j][0] = LDB(b, j, 0); b01[j][1] = LDB(b, j, 1); }                 \
    if (s_ + 1 < NT) { STAGE_A(nb, 0, 1, s_ + 1); STAGE_A(nb, 1, 1, s_ + 1); }\
    asm volatile("s_waitcnt lgkmcnt(8)" ::: "memory");                        \
    SFENCE(); __builtin_amdgcn_s_barrier();                                   \
    asm volatile("s_waitcnt lgkmcnt(0)" ::: "memory");                        \
    MFMA16(0, 0, b01)                                                         \
    SFENCE(); __builtin_amdgcn_s_barrier(); SFENCE();                         \
    /* -------- P2: Q01 -------- */                                           \
    _Pragma("unroll") for (int j = 0; j < 2; j++) {                           \
        b23[j][0] = LDB(b, 2 + j, 0); b23[j][1] = LDB(b, 2 + j, 1); }         \
    if (s_ + 2 < NT) { STAGE_A(b, 0, 0, s_ + 2); STAGE_A(b, 1, 0, s_ + 2); }  \
    SFENCE(); __builtin_amdgcn_s_barrier();                                   \
    asm volatile("s_waitcnt lgkmcnt(0)" ::: "memory");                        \
    MFMA16(0, 2, b23)                                                         \
    SFENCE(); __builtin_amdgcn_s_barrier(); SFENCE();                         \
    /* -------- P3: Q10 -------- */                                           \
    _Pragma("unroll") for (int i = 0; i < 4; i++) {                           \
        af[i][0] = LDA(b, 4 + i, 0); af[i][1] = LDA(b, 4 + i, 1); }           \
    if (s_ + 2 < NT) { STAGE_B(b, 0, 0, s_ + 2); STAGE_B(b, 0, 1, s_ + 2); }  \
    SFENCE(); __builtin_amdgcn_s_barrier();                                   \
    asm volatile("s_waitcnt lgkmcnt(0)" ::: "memory");                        \
    MFMA16(4, 0, b01)                                                         \
    SFENCE(); __builtin_amdgcn_s_barrier(); SFENCE();                         \
    /* -------- P4: Q11 -------- */                                           \
    if (s_ + 2 < NT) { STAGE_B(b, 1, 0, s_ + 2); STAGE_B(b, 1, 1, s_ + 2); }  \
    MFMA16(4, 2, b23)                                                         \
    if (s_ + 2 < NT) asm volatile("s_waitcnt vmcnt(6)" ::: "memory");         \
    else             asm volatile("s_waitcnt vmcnt(0)" ::: "memory");         \
    SFENCE(); __builtin_amdgcn_s_barrier(); SFENCE();                         \
  }

    // ---- prologue: tile0 complete (8, buf0) + tile1 {A*r0, B all} (6, buf1)
    STAGE_A(0, 0, 0, 0); STAGE_A(0, 1, 0, 0);
    STAGE_A(0, 0, 1, 0); STAGE_A(0, 1, 1, 0);
    STAGE_B(0, 0, 0, 0); STAGE_B(0, 0, 1, 0);
    STAGE_B(0, 1, 0, 0); STAGE_B(0, 1, 1, 0);
    STAGE_A(1, 0, 0, 1); STAGE_A(1, 1, 0, 1);
    STAGE_B(1, 0, 0, 1); STAGE_B(1, 0, 1, 1);
    STAGE_B(1, 1, 0, 1); STAGE_B(1, 1, 1, 1);
    asm volatile("s_waitcnt vmcnt(6)" ::: "memory");  // tile0 landed
    __builtin_amdgcn_s_barrier();
    SFENCE();

    // Even tiles -> buf0, odd -> buf1; all LDS indices compile-time constant.
    for (int s = 0; s < NT; s += 2) {
        KTILE(0, 1, s)
        KTILE(1, 0, s + 1)
    }

    // ---- epilogue: C/D layout col = lane&15, row = (lane>>4)*4 + reg ----
    float bv[4];
#pragma unroll
    for (int j = 0; j < 4; j++)
        bv[j] = bias[n0 + wn * 64 + j * 16 + lm];
    const int row_base = m0 + wm * 128 + h4 * 4;
    const int col_base = n0 + wn * 64 + lm;
#pragma unroll
    for (int i = 0; i < 8; i++)
#pragma unroll
        for (int j = 0; j < 4; j++) {
            const int col = col_base + j * 16;
#pragma unroll
            for (int r = 0; r < 4; r++)
                C[(size_t)(row_base + i * 16 + r) * N_DIM + col] =
                    acc[i][j][r] + bv[j];
        }
}

extern "C" void kernel_launch(void* const* d_in, const int* in_sizes, int n_in,
                              void* d_out, int out_size, void* d_ws, size_t ws_size,
                              hipStream_t stream) {
    const float* x    = (const float*)d_in[0];   // [4,2048,4096] fp32
    const float* w    = (const float*)d_in[1];   // [4096,4096] fp32
    const float* bias = (const float*)d_in[2];   // [4096] fp32
    const float* mask = (const float*)d_in[3];   // [4096,4096] fp32
    float* out = (float*)d_out;                  // [8192,4096] fp32

    __hip_bfloat16* xb = (__hip_bfloat16*)d_ws;                    // 64 MiB
    __hip_bfloat16* wb = xb + (size_t)M_DIM * K_DIM;               // 32 MiB

    cvt_all<<<dim3(CVT_GRID), dim3(256), 0, stream>>>(
        (const float4*)x, (const float4*)w, (const float4*)mask,
        (uint4*)xb, (uint4*)wb, M_DIM * K_DIM / 8, N_DIM * K_DIM / 8);
    gemm_8phase<<<dim3(512), dim3(512), 0, stream>>>(xb, wb, bias, out);
}